// Round 8
// baseline (6519.067 us; speedup 1.0000x reference)
//
#include <hip/hip_runtime.h>
#include <hip/hip_bf16.h>

// Problem constants
#define BATCH 64
#define TT 512
#define UNITS 512
#define NOUT 256
#define NSPEED 20
#define NHD 50
#define NFEAT 70

// Derived constants
#define SPEED_COEF (-800.0f)                  // -0.5/sd^2, sd = 0.5/20
#define SPEED_STEP (0.5f / 19.0f)             // linspace(0,0.5,20)
#define HD_STEP (6.28318530718f / 49.0f)      // linspace(0,2pi,50)
#define KAPPA 6.2831853f
#define C_HD 0.9783857f                       // 1 / (2*pi*i0e(2*pi)), i0e(2pi)=0.162671

#define GSPLIT 4
#define CPB 128  // columns per scan block

// ---------------------------------------------------------------------------
// Kernel P: repack W_rec f32 [k][col] -> per-slice float4 tiles:
// wp[s][k4][col] (s-slice contiguous 256 KB) where element =
// (W[4k4+0][s*128+col], ..., W[4k4+3][s*128+col]). Also zero the barrier
// counters (ws is poisoned 0xAA before every launch).
// ---------------------------------------------------------------------------
__global__ __launch_bounds__(256) void prep_w4s_kernel(
    const float* __restrict__ W, float4* __restrict__ wp,
    unsigned* __restrict__ cnt) {
  int idx = blockIdx.x * 256 + threadIdx.x;  // 65536
  int s = idx >> 14, k4 = (idx >> 7) & 127, col = idx & 127;
  int gcol = s * CPB + col;
  const float* w0 = W + (size_t)(k4 * 4) * UNITS + gcol;
  wp[idx] = make_float4(w0[0], w0[UNITS], w0[2 * UNITS], w0[3 * UNITS]);
  if (idx < BATCH) cnt[idx * 32] = 0u;
}

// ---------------------------------------------------------------------------
// Kernel A: RBF/VonMises features + drive = sf@W_speed + hf@W_hd + b_rec
// ---------------------------------------------------------------------------
__global__ __launch_bounds__(256) void feat_drive_kernel(
    const float* __restrict__ vel, const float* __restrict__ W_speed,
    const float* __restrict__ W_hd, const float* __restrict__ b_rec,
    float* __restrict__ drive) {
  __shared__ float feats[64][NFEAT];
  const int row0 = blockIdx.x * 64;
  const int tid = threadIdx.x;

  for (int j = tid; j < 64 * NFEAT; j += 256) {
    int row = j / NFEAT, k = j % NFEAT;
    int grow = row0 + row;
    float f;
    if (k < NSPEED) {
      float s = vel[grow * 2 + 0];
      float d = s - (float)k * SPEED_STEP;
      f = __expf(SPEED_COEF * d * d);
    } else {
      float hd = vel[grow * 2 + 1];
      float c = (float)(k - NSPEED) * HD_STEP;
      f = C_HD * __expf(KAPPA * (__cosf(hd - c) - 1.0f));
    }
    feats[row][k] = f;
  }
  __syncthreads();

  const float2* Ws2 = (const float2*)W_speed;  // [20][256]
  const float2* Wh2 = (const float2*)W_hd;     // [50][256]
  float2 br = ((const float2*)b_rec)[tid];

  for (int r = 0; r < 64; ++r) {
    float a0 = br.x, a1 = br.y;
#pragma unroll
    for (int k = 0; k < NSPEED; ++k) {
      float f = feats[r][k];
      float2 w = Ws2[k * 256 + tid];
      a0 = fmaf(f, w.x, a0);
      a1 = fmaf(f, w.y, a1);
    }
#pragma unroll 10
    for (int k = 0; k < NHD; ++k) {
      float f = feats[r][NSPEED + k];
      float2 w = Wh2[k * 256 + tid];
      a0 = fmaf(f, w.x, a0);
      a1 = fmaf(f, w.y, a1);
    }
    ((float2*)drive)[(size_t)(row0 + r) * 256 + tid] = make_float2(a0, a1);
  }
}

// ---------------------------------------------------------------------------
// Kernel B: col-split RNN scan. 256 blocks = (batch b, slice s); block owns
// 128 cols, streams its contiguous 256 KB W-slice per step (per-CU L1-fill
// roofline was the R6 wall at 1 MB/step/CU). Per-batch 4-party spin barrier
// on a monotonic device-scope counter; h exchanged via hstates[b][t].
// ---------------------------------------------------------------------------
__global__ __launch_bounds__(1024) void rnn_scan4_kernel(
    const float4* __restrict__ wp, const float* __restrict__ drive,
    const float* __restrict__ start_state, float* __restrict__ hstates,
    unsigned* __restrict__ cnt) {
  __shared__ __align__(16) float hf[UNITS];  // full h (current step input)
  __shared__ float pt[1024];                 // k-group partials
  const int bid = blockIdx.x;
  const int b = bid >> 2, s = bid & 3;
  const int tid = threadIdx.x;
  const int col = tid & (CPB - 1);  // 0..127
  const int kg = tid >> 7;          // 0..7 (wave-uniform)
  const int scol = s * CPB + col;

  if (tid < 128) ((float4*)hf)[tid] = ((const float4*)start_state)[tid];
  __syncthreads();

  const float4* wb = wp + (s << 14) + (kg << 11) + col;  // slice base
  const float4* hfv = (const float4*)hf + (kg << 4);     // 16 float4 per kg
  const float* D = drive + (size_t)b * TT * UNITS;
  float* H = hstates + (size_t)b * TT * UNITS;
  unsigned* c = cnt + (b << 5);  // one 128B line per batch

  for (int t = 0; t < TT; ++t) {
    float a0 = 0.f, a1 = 0.f, a2 = 0.f, a3 = 0.f;
#pragma unroll
    for (int g = 0; g < 16; ++g) {
      float4 w = wb[g << 7];  // coalesced 1KB wave-load, contiguous slice
      float4 h4 = hfv[g];     // wave-uniform LDS broadcast
      a0 = fmaf(h4.x, w.x, a0);
      a1 = fmaf(h4.y, w.y, a1);
      a2 = fmaf(h4.z, w.z, a2);
      a3 = fmaf(h4.w, w.w, a3);
    }
    pt[tid] = (a0 + a1) + (a2 + a3);
    __syncthreads();
    if (tid < 128) {
      float sum = 0.f;
#pragma unroll
      for (int j = 0; j < 8; ++j) sum += pt[col + (j << 7)];
      float hn = fmaxf(sum + D[t * UNITS + scol], 0.0f);
      H[t * UNITS + scol] = hn;  // own slice of h_t (also the output)
    }
    __syncthreads();  // drains store (vmcnt0 before s_barrier)
    if (t == TT - 1) break;
    if (tid == 0) {
      // release: publish our slice, then arrive
      __hip_atomic_fetch_add(c, 1u, __ATOMIC_RELEASE,
                             __HIP_MEMORY_SCOPE_AGENT);
      unsigned tgt = (unsigned)(GSPLIT * (t + 1));
      while (__hip_atomic_load(c, __ATOMIC_RELAXED,
                               __HIP_MEMORY_SCOPE_AGENT) < tgt)
        __builtin_amdgcn_s_sleep(2);
    }
    __syncthreads();
    if (tid < 128) {
      __threadfence();  // acquire: invalidate stale L1/L2 before remote read
      ((float4*)hf)[tid] = ((const float4*)&H[t * UNITS])[tid];
    }
    __syncthreads();
  }
}

// ---------------------------------------------------------------------------
// Kernel C: out = relu(hstates @ W_out + b_out); M=32768, N=256, K=512
// ---------------------------------------------------------------------------
__global__ __launch_bounds__(256) void out_gemm_kernel(
    const float* __restrict__ A,    // [32768][512]
    const float* __restrict__ Bm,   // [512][256]
    const float* __restrict__ b_out,
    float* __restrict__ C) {        // [32768][256]
  __shared__ float As[32][68];  // transposed, padded
  __shared__ float Bs[32][64];
  const int bm = blockIdx.x, bn = blockIdx.y;
  const int tid = threadIdx.x;
  const int tm = tid / 16, tn = tid % 16;

  float acc[4][4] = {{0.f}};

  for (int k0 = 0; k0 < UNITS; k0 += 32) {
    {
      int ar = tid / 8;
      int ac = (tid % 8) * 4;
#pragma unroll
      for (int p = 0; p < 2; ++p) {
        int row = ar + p * 32;
        float4 v = *(const float4*)&A[(size_t)(bm * 64 + row) * 512 + k0 + ac];
        As[ac + 0][row] = v.x;
        As[ac + 1][row] = v.y;
        As[ac + 2][row] = v.z;
        As[ac + 3][row] = v.w;
      }
      int brr = tid / 16;
      int bc = (tid % 16) * 4;
#pragma unroll
      for (int p = 0; p < 2; ++p) {
        int row = brr + p * 16;
        *(float4*)&Bs[row][bc] =
            *(const float4*)&Bm[(size_t)(k0 + row) * 256 + bn * 64 + bc];
      }
    }
    __syncthreads();
#pragma unroll
    for (int kk = 0; kk < 32; ++kk) {
      float4 av = *(const float4*)&As[kk][tm * 4];
      float4 bv = *(const float4*)&Bs[kk][tn * 4];
      acc[0][0] = fmaf(av.x, bv.x, acc[0][0]);
      acc[0][1] = fmaf(av.x, bv.y, acc[0][1]);
      acc[0][2] = fmaf(av.x, bv.z, acc[0][2]);
      acc[0][3] = fmaf(av.x, bv.w, acc[0][3]);
      acc[1][0] = fmaf(av.y, bv.x, acc[1][0]);
      acc[1][1] = fmaf(av.y, bv.y, acc[1][1]);
      acc[1][2] = fmaf(av.y, bv.z, acc[1][2]);
      acc[1][3] = fmaf(av.y, bv.w, acc[1][3]);
      acc[2][0] = fmaf(av.z, bv.x, acc[2][0]);
      acc[2][1] = fmaf(av.z, bv.y, acc[2][1]);
      acc[2][2] = fmaf(av.z, bv.z, acc[2][2]);
      acc[2][3] = fmaf(av.z, bv.w, acc[2][3]);
      acc[3][0] = fmaf(av.w, bv.x, acc[3][0]);
      acc[3][1] = fmaf(av.w, bv.y, acc[3][1]);
      acc[3][2] = fmaf(av.w, bv.z, acc[3][2]);
      acc[3][3] = fmaf(av.w, bv.w, acc[3][3]);
    }
    __syncthreads();
  }

  float4 bo = *(const float4*)&b_out[bn * 64 + tn * 4];
#pragma unroll
  for (int i = 0; i < 4; ++i) {
    int row = bm * 64 + tm * 4 + i;
    float4 o;
    o.x = fmaxf(acc[i][0] + bo.x, 0.0f);
    o.y = fmaxf(acc[i][1] + bo.y, 0.0f);
    o.z = fmaxf(acc[i][2] + bo.z, 0.0f);
    o.w = fmaxf(acc[i][3] + bo.w, 0.0f);
    *(float4*)&C[(size_t)row * 256 + bn * 64 + tn * 4] = o;
  }
}

// ---------------------------------------------------------------------------
// Kernel D1: EC[b,n,:] = (sum_t out*r) / (sum_t out + T*1e-10)
// ---------------------------------------------------------------------------
__global__ __launch_bounds__(256) void ec_kernel(
    const float* __restrict__ out, const float* __restrict__ r,
    float* __restrict__ EC) {  // [64][256][2]
  const int b = blockIdx.x, n = threadIdx.x;
  const float* ob = out + (size_t)b * TT * NOUT;
  const float2* rb = (const float2*)r + (size_t)b * TT;
  float s = 0.0f, e0 = 0.0f, e1 = 0.0f;
  for (int t = 0; t < TT; ++t) {
    float o = ob[t * NOUT + n];
    float2 rv = rb[t];
    s += o;
    e0 = fmaf(o, rv.x, e0);
    e1 = fmaf(o, rv.y, e1);
  }
  float inv = 1.0f / (s + 5.12e-8f);  // + T*1e-10
  ((float2*)EC)[b * NOUT + n] = make_float2(e0 * inv, e1 * inv);
}

// ---------------------------------------------------------------------------
// Kernel D2: EP[b,t,:] = (sum_n out*EC) / (sum_n out + N*1e-10)
// ---------------------------------------------------------------------------
__global__ __launch_bounds__(256) void ep_kernel(
    const float* __restrict__ out, const float* __restrict__ EC,
    float* __restrict__ EP) {
  const int b = blockIdx.x;
  const int tid = threadIdx.x;
  const int lane = tid & 63, wave = tid >> 6;
  __shared__ float ec0[NOUT], ec1[NOUT];

  float2 e = ((const float2*)EC)[b * NOUT + tid];
  ec0[tid] = e.x;
  ec1[tid] = e.y;
  __syncthreads();

  float4 c0 = *(const float4*)&ec0[lane * 4];
  float4 c1 = *(const float4*)&ec1[lane * 4];

  const float* ob = out + (size_t)b * TT * NOUT;
  float2* epb = (float2*)EP + (size_t)b * TT;

  for (int t = wave; t < TT; t += 4) {
    float4 o = *(const float4*)&ob[t * NOUT + lane * 4];
    float s = o.x + o.y + o.z + o.w;
    float a0 = o.x * c0.x + o.y * c0.y + o.z * c0.z + o.w * c0.w;
    float a1 = o.x * c1.x + o.y * c1.y + o.z * c1.z + o.w * c1.w;
#pragma unroll
    for (int off = 32; off > 0; off >>= 1) {
      s += __shfl_down(s, off);
      a0 += __shfl_down(a0, off);
      a1 += __shfl_down(a1, off);
    }
    if (lane == 0) {
      float inv = 1.0f / (s + 2.56e-8f);  // + NOUT*1e-10
      epb[t] = make_float2(a0 * inv, a1 * inv);
    }
  }
}

// ---------------------------------------------------------------------------
extern "C" void kernel_launch(void* const* d_in, const int* in_sizes, int n_in,
                              void* d_out, int out_size, void* d_ws,
                              size_t ws_size, hipStream_t stream) {
  const float* vel = (const float*)d_in[0];
  const float* r = (const float*)d_in[1];
  const float* start_state = (const float*)d_in[2];
  const float* W_speed = (const float*)d_in[3];
  const float* W_hd = (const float*)d_in[4];
  const float* W_rec = (const float*)d_in[5];
  const float* b_rec = (const float*)d_in[6];
  const float* W_out = (const float*)d_in[7];
  const float* b_out = (const float*)d_in[8];
  float* EP = (float*)d_out;

  char* ws = (char*)d_ws;
  float* drive = (float*)ws;                            // 64 MB
  float* hstates = (float*)(ws + (size_t)67108864);     // 64 MB
  float* outbuf = (float*)ws;                           // reuses drive region
  float4* wpack = (float4*)(ws + (size_t)134217728);    // 1 MB repacked W_rec
  unsigned* cnt = (unsigned*)(ws + (size_t)135266304);  // 64 x 128B counters
  float* EC = (float*)(ws + (size_t)135274496);         // 128 KB

  prep_w4s_kernel<<<256, 256, 0, stream>>>(W_rec, wpack, cnt);
  feat_drive_kernel<<<512, 256, 0, stream>>>(vel, W_speed, W_hd, b_rec, drive);
  rnn_scan4_kernel<<<256, 1024, 0, stream>>>(wpack, drive, start_state,
                                             hstates, cnt);
  out_gemm_kernel<<<dim3(512, 4), 256, 0, stream>>>(hstates, W_out, b_out,
                                                    outbuf);
  ec_kernel<<<64, 256, 0, stream>>>(outbuf, r, EC);
  ep_kernel<<<64, 256, 0, stream>>>(outbuf, EC, EP);
}

// Round 10
// 2799.289 us; speedup vs baseline: 2.3288x; 2.3288x over previous
//
#include <hip/hip_runtime.h>
#include <hip/hip_bf16.h>

// Problem constants
#define BATCH 64
#define TT 512
#define UNITS 512
#define NOUT 256
#define NSPEED 20
#define NHD 50
#define NFEAT 70

// Derived constants
#define SPEED_COEF (-800.0f)                  // -0.5/sd^2, sd = 0.5/20
#define SPEED_STEP (0.5f / 19.0f)             // linspace(0,0.5,20)
#define HD_STEP (6.28318530718f / 49.0f)      // linspace(0,2pi,50)
#define KAPPA 6.2831853f
#define C_HD 0.9783857f                       // 1 / (2*pi*i0e(2*pi)), i0e(2pi)=0.162671

#define ESCALE 4194304.0f                     // 2^22
#define EINV 2.38418579e-7f                   // 2^-22

// ---------------------------------------------------------------------------
// Kernel P: quantize E = W_rec - I to int16 (scale 2^22), packed [k8][col]
// as uint4 = 8 int16 (k ascending, low half = even k). 512 KB total.
// max|E| ~ 0.0047 << 32767*2^-22 = 0.0078 range; clamp as safety.
// ---------------------------------------------------------------------------
__global__ __launch_bounds__(256) void prep_ei_kernel(
    const float* __restrict__ W, uint4* __restrict__ ep) {
  int idx = blockIdx.x * 256 + threadIdx.x;  // 32768 = 64 k8-groups * 512 cols
  int k8 = idx >> 9, col = idx & 511;
  unsigned u[4];
#pragma unroll
  for (int j = 0; j < 4; ++j) {
    int k0 = k8 * 8 + 2 * j;
    float a = W[(size_t)k0 * UNITS + col] - (k0 == col ? 1.0f : 0.0f);
    float b = W[(size_t)(k0 + 1) * UNITS + col] - (k0 + 1 == col ? 1.0f : 0.0f);
    int ia = __float2int_rn(a * ESCALE);
    int ib = __float2int_rn(b * ESCALE);
    ia = ia < -32767 ? -32767 : (ia > 32767 ? 32767 : ia);
    ib = ib < -32767 ? -32767 : (ib > 32767 ? 32767 : ib);
    u[j] = ((unsigned)ia & 0xffffu) | ((unsigned)ib << 16);
  }
  ep[idx] = make_uint4(u[0], u[1], u[2], u[3]);
}

// ---------------------------------------------------------------------------
// Kernel A: RBF/VonMises features + drive = sf@W_speed + hf@W_hd + b_rec
// ---------------------------------------------------------------------------
__global__ __launch_bounds__(256) void feat_drive_kernel(
    const float* __restrict__ vel, const float* __restrict__ W_speed,
    const float* __restrict__ W_hd, const float* __restrict__ b_rec,
    float* __restrict__ drive) {
  __shared__ float feats[64][NFEAT];
  const int row0 = blockIdx.x * 64;
  const int tid = threadIdx.x;

  for (int j = tid; j < 64 * NFEAT; j += 256) {
    int row = j / NFEAT, k = j % NFEAT;
    int grow = row0 + row;
    float f;
    if (k < NSPEED) {
      float s = vel[grow * 2 + 0];
      float d = s - (float)k * SPEED_STEP;
      f = __expf(SPEED_COEF * d * d);
    } else {
      float hd = vel[grow * 2 + 1];
      float c = (float)(k - NSPEED) * HD_STEP;
      f = C_HD * __expf(KAPPA * (__cosf(hd - c) - 1.0f));
    }
    feats[row][k] = f;
  }
  __syncthreads();

  const float2* Ws2 = (const float2*)W_speed;  // [20][256]
  const float2* Wh2 = (const float2*)W_hd;     // [50][256]
  float2 br = ((const float2*)b_rec)[tid];

  for (int r = 0; r < 64; ++r) {
    float a0 = br.x, a1 = br.y;
#pragma unroll
    for (int k = 0; k < NSPEED; ++k) {
      float f = feats[r][k];
      float2 w = Ws2[k * 256 + tid];
      a0 = fmaf(f, w.x, a0);
      a1 = fmaf(f, w.y, a1);
    }
#pragma unroll 10
    for (int k = 0; k < NHD; ++k) {
      float f = feats[r][NSPEED + k];
      float2 w = Wh2[k * 256 + tid];
      a0 = fmaf(f, w.x, a0);
      a1 = fmaf(f, w.y, a1);
    }
    ((float2*)drive)[(size_t)(row0 + r) * 256 + tid] = make_float2(a0, a1);
  }
}

// ---------------------------------------------------------------------------
// Kernel B: sequential RNN scan, int16 E-weights (2 B/elem halves the
// per-CU L2->L1 fill stream that was the R6 roofline). 64 blocks x 1024
// threads; thread = (col, k-half); diag identity applied exactly in f32.
// h_new = relu(h + (Sum E_int*h)*2^-22 + d).
// ---------------------------------------------------------------------------
__global__ __launch_bounds__(1024) void rnn_scan5_kernel(
    const uint4* __restrict__ ep, const float* __restrict__ drive,
    const float* __restrict__ start_state, float* __restrict__ hstates) {
  __shared__ __align__(16) float hf[UNITS];
  __shared__ float pt[UNITS];
  const int b = blockIdx.x;
  const int tid = threadIdx.x;
  const int col = tid & 511;
  const int ks = tid >> 9;  // k-half: wave-uniform

  if (tid < UNITS) hf[tid] = start_state[tid];
  __syncthreads();

  const uint4* eb = ep + (ks << 14) + col;           // (ks*32 + g)*512 + col
  const float4* hfv = (const float4*)hf + (ks << 6);  // 64 float4 per half
  const float* D = drive + (size_t)b * TT * UNITS;
  float* H = hstates + (size_t)b * TT * UNITS;

  for (int t = 0; t < TT; ++t) {
    float a0 = 0.f, a1 = 0.f, a2 = 0.f, a3 = 0.f;
#pragma unroll 8
    for (int g = 0; g < 32; ++g) {
      uint4 e = eb[g << 9];       // 16B coalesced: 8 int16 weights
      float4 ha = hfv[2 * g];     // h[k..k+3] wave-uniform LDS broadcast
      float4 hb = hfv[2 * g + 1]; // h[k+4..k+7]
      a0 = fmaf((float)((int)(e.x << 16) >> 16), ha.x, a0);
      a1 = fmaf((float)((int)e.x >> 16), ha.y, a1);
      a2 = fmaf((float)((int)(e.y << 16) >> 16), ha.z, a2);
      a3 = fmaf((float)((int)e.y >> 16), ha.w, a3);
      a0 = fmaf((float)((int)(e.z << 16) >> 16), hb.x, a0);
      a1 = fmaf((float)((int)e.z >> 16), hb.y, a1);
      a2 = fmaf((float)((int)(e.w << 16) >> 16), hb.z, a2);
      a3 = fmaf((float)((int)e.w >> 16), hb.w, a3);
    }
    float acc = (a0 + a1) + (a2 + a3);
    if (ks) pt[col] = acc;
    __syncthreads();
    if (!ks) {
      float hn = fmaxf(fmaf(acc + pt[col], EINV, hf[col] + D[t * UNITS + col]),
                       0.0f);
      hf[col] = hn;
      H[t * UNITS + col] = hn;
    }
    __syncthreads();
  }
}

// ---------------------------------------------------------------------------
// Kernel C: out = relu(hstates @ W_out + b_out); M=32768, N=256, K=512
// ---------------------------------------------------------------------------
__global__ __launch_bounds__(256) void out_gemm_kernel(
    const float* __restrict__ A,    // [32768][512]
    const float* __restrict__ Bm,   // [512][256]
    const float* __restrict__ b_out,
    float* __restrict__ C) {        // [32768][256]
  __shared__ float As[32][68];  // transposed, padded
  __shared__ float Bs[32][64];
  const int bm = blockIdx.x, bn = blockIdx.y;
  const int tid = threadIdx.x;
  const int tm = tid / 16, tn = tid % 16;

  float acc[4][4] = {{0.f}};

  for (int k0 = 0; k0 < UNITS; k0 += 32) {
    {
      int ar = tid / 8;
      int ac = (tid % 8) * 4;
#pragma unroll
      for (int p = 0; p < 2; ++p) {
        int row = ar + p * 32;
        float4 v = *(const float4*)&A[(size_t)(bm * 64 + row) * 512 + k0 + ac];
        As[ac + 0][row] = v.x;
        As[ac + 1][row] = v.y;
        As[ac + 2][row] = v.z;
        As[ac + 3][row] = v.w;
      }
      int brr = tid / 16;
      int bc = (tid % 16) * 4;
#pragma unroll
      for (int p = 0; p < 2; ++p) {
        int row = brr + p * 16;
        *(float4*)&Bs[row][bc] =
            *(const float4*)&Bm[(size_t)(k0 + row) * 256 + bn * 64 + bc];
      }
    }
    __syncthreads();
#pragma unroll
    for (int kk = 0; kk < 32; ++kk) {
      float4 av = *(const float4*)&As[kk][tm * 4];
      float4 bv = *(const float4*)&Bs[kk][tn * 4];
      acc[0][0] = fmaf(av.x, bv.x, acc[0][0]);
      acc[0][1] = fmaf(av.x, bv.y, acc[0][1]);
      acc[0][2] = fmaf(av.x, bv.z, acc[0][2]);
      acc[0][3] = fmaf(av.x, bv.w, acc[0][3]);
      acc[1][0] = fmaf(av.y, bv.x, acc[1][0]);
      acc[1][1] = fmaf(av.y, bv.y, acc[1][1]);
      acc[1][2] = fmaf(av.y, bv.z, acc[1][2]);
      acc[1][3] = fmaf(av.y, bv.w, acc[1][3]);
      acc[2][0] = fmaf(av.z, bv.x, acc[2][0]);
      acc[2][1] = fmaf(av.z, bv.y, acc[2][1]);
      acc[2][2] = fmaf(av.z, bv.z, acc[2][2]);
      acc[2][3] = fmaf(av.z, bv.w, acc[2][3]);
      acc[3][0] = fmaf(av.w, bv.x, acc[3][0]);
      acc[3][1] = fmaf(av.w, bv.y, acc[3][1]);
      acc[3][2] = fmaf(av.w, bv.z, acc[3][2]);
      acc[3][3] = fmaf(av.w, bv.w, acc[3][3]);
    }
    __syncthreads();
  }

  float4 bo = *(const float4*)&b_out[bn * 64 + tn * 4];
#pragma unroll
  for (int i = 0; i < 4; ++i) {
    int row = bm * 64 + tm * 4 + i;
    float4 o;
    o.x = fmaxf(acc[i][0] + bo.x, 0.0f);
    o.y = fmaxf(acc[i][1] + bo.y, 0.0f);
    o.z = fmaxf(acc[i][2] + bo.z, 0.0f);
    o.w = fmaxf(acc[i][3] + bo.w, 0.0f);
    *(float4*)&C[(size_t)row * 256 + bn * 64 + tn * 4] = o;
  }
}

// ---------------------------------------------------------------------------
// Kernel D1: EC[b,n,:] = (sum_t out*r) / (sum_t out + T*1e-10)
// ---------------------------------------------------------------------------
__global__ __launch_bounds__(256) void ec_kernel(
    const float* __restrict__ out, const float* __restrict__ r,
    float* __restrict__ EC) {  // [64][256][2]
  const int b = blockIdx.x, n = threadIdx.x;
  const float* ob = out + (size_t)b * TT * NOUT;
  const float2* rb = (const float2*)r + (size_t)b * TT;
  float s = 0.0f, e0 = 0.0f, e1 = 0.0f;
  for (int t = 0; t < TT; ++t) {
    float o = ob[t * NOUT + n];
    float2 rv = rb[t];
    s += o;
    e0 = fmaf(o, rv.x, e0);
    e1 = fmaf(o, rv.y, e1);
  }
  float inv = 1.0f / (s + 5.12e-8f);  // + T*1e-10
  ((float2*)EC)[b * NOUT + n] = make_float2(e0 * inv, e1 * inv);
}

// ---------------------------------------------------------------------------
// Kernel D2: EP[b,t,:] = (sum_n out*EC) / (sum_n out + N*1e-10)
// ---------------------------------------------------------------------------
__global__ __launch_bounds__(256) void ep_kernel(
    const float* __restrict__ out, const float* __restrict__ EC,
    float* __restrict__ EP) {
  const int b = blockIdx.x;
  const int tid = threadIdx.x;
  const int lane = tid & 63, wave = tid >> 6;
  __shared__ float ec0[NOUT], ec1[NOUT];

  float2 e = ((const float2*)EC)[b * NOUT + tid];
  ec0[tid] = e.x;
  ec1[tid] = e.y;
  __syncthreads();

  float4 c0 = *(const float4*)&ec0[lane * 4];
  float4 c1 = *(const float4*)&ec1[lane * 4];

  const float* ob = out + (size_t)b * TT * NOUT;
  float2* epb = (float2*)EP + (size_t)b * TT;

  for (int t = wave; t < TT; t += 4) {
    float4 o = *(const float4*)&ob[t * NOUT + lane * 4];
    float s = o.x + o.y + o.z + o.w;
    float a0 = o.x * c0.x + o.y * c0.y + o.z * c0.z + o.w * c0.w;
    float a1 = o.x * c1.x + o.y * c1.y + o.z * c1.z + o.w * c1.w;
#pragma unroll
    for (int off = 32; off > 0; off >>= 1) {
      s += __shfl_down(s, off);
      a0 += __shfl_down(a0, off);
      a1 += __shfl_down(a1, off);
    }
    if (lane == 0) {
      float inv = 1.0f / (s + 2.56e-8f);  // + NOUT*1e-10
      epb[t] = make_float2(a0 * inv, a1 * inv);
    }
  }
}

// ---------------------------------------------------------------------------
extern "C" void kernel_launch(void* const* d_in, const int* in_sizes, int n_in,
                              void* d_out, int out_size, void* d_ws,
                              size_t ws_size, hipStream_t stream) {
  const float* vel = (const float*)d_in[0];
  const float* r = (const float*)d_in[1];
  const float* start_state = (const float*)d_in[2];
  const float* W_speed = (const float*)d_in[3];
  const float* W_hd = (const float*)d_in[4];
  const float* W_rec = (const float*)d_in[5];
  const float* b_rec = (const float*)d_in[6];
  const float* W_out = (const float*)d_in[7];
  const float* b_out = (const float*)d_in[8];
  float* EP = (float*)d_out;

  char* ws = (char*)d_ws;
  float* drive = (float*)ws;                            // 64 MB
  float* hstates = (float*)(ws + (size_t)67108864);     // 64 MB
  float* outbuf = (float*)ws;                           // reuses drive region
  uint4* epack = (uint4*)(ws + (size_t)134217728);      // 512 KB int16 E
  float* EC = (float*)(ws + (size_t)134742016);         // 128 KB

  prep_ei_kernel<<<128, 256, 0, stream>>>(W_rec, epack);
  feat_drive_kernel<<<512, 256, 0, stream>>>(vel, W_speed, W_hd, b_rec, drive);
  rnn_scan5_kernel<<<64, 1024, 0, stream>>>(epack, drive, start_state,
                                            hstates);
  out_gemm_kernel<<<dim3(512, 4), 256, 0, stream>>>(hstates, W_out, b_out,
                                                    outbuf);
  ec_kernel<<<64, 256, 0, stream>>>(outbuf, r, EC);
  ep_kernel<<<64, 256, 0, stream>>>(outbuf, EC, EP);
}

// Round 12
// 1392.604 us; speedup vs baseline: 4.6812x; 2.0101x over previous
//
#include <hip/hip_runtime.h>
#include <hip/hip_bf16.h>

// Problem constants
#define BATCH 64
#define TT 512
#define UNITS 512
#define NOUT 256
#define NSPEED 20
#define NHD 50
#define NFEAT 70

// Derived constants
#define SPEED_COEF (-800.0f)                  // -0.5/sd^2, sd = 0.5/20
#define SPEED_STEP (0.5f / 19.0f)             // linspace(0,0.5,20)
#define HD_STEP (6.28318530718f / 49.0f)      // linspace(0,2pi,50)
#define KAPPA 6.2831853f
#define C_HD 0.9783857f                       // 1 / (2*pi*i0e(2*pi)), i0e(2pi)=0.162671

#define GS 4     // CU-slices per batch
#define CPB 128  // columns per scan block

// ---------------------------------------------------------------------------
// Kernel P: repack W_rec f32 [k][col] -> per-slice float4 tiles:
// wp[s*16384 + k4*128 + col] = (W[4k4+0..3][s*128+col]); zero barrier
// counters via agent-scope atomic stores (ws poisoned 0xAA each launch).
// ---------------------------------------------------------------------------
__global__ __launch_bounds__(256) void prep_w4s_kernel(
    const float* __restrict__ W, float4* __restrict__ wp,
    unsigned* __restrict__ cnt) {
  int idx = blockIdx.x * 256 + threadIdx.x;  // 65536
  int s = idx >> 14, k4 = (idx >> 7) & 127, col = idx & 127;
  int gcol = s * CPB + col;
  const float* w0 = W + (size_t)(k4 * 4) * UNITS + gcol;
  wp[idx] = make_float4(w0[0], w0[UNITS], w0[2 * UNITS], w0[3 * UNITS]);
  if (idx < BATCH)
    __hip_atomic_store(&cnt[idx * 32], 0u, __ATOMIC_RELAXED,
                       __HIP_MEMORY_SCOPE_AGENT);
}

// ---------------------------------------------------------------------------
// Kernel A: RBF/VonMises features + drive = sf@W_speed + hf@W_hd + b_rec
// ---------------------------------------------------------------------------
__global__ __launch_bounds__(256) void feat_drive_kernel(
    const float* __restrict__ vel, const float* __restrict__ W_speed,
    const float* __restrict__ W_hd, const float* __restrict__ b_rec,
    float* __restrict__ drive) {
  __shared__ float feats[64][NFEAT];
  const int row0 = blockIdx.x * 64;
  const int tid = threadIdx.x;

  for (int j = tid; j < 64 * NFEAT; j += 256) {
    int row = j / NFEAT, k = j % NFEAT;
    int grow = row0 + row;
    float f;
    if (k < NSPEED) {
      float s = vel[grow * 2 + 0];
      float d = s - (float)k * SPEED_STEP;
      f = __expf(SPEED_COEF * d * d);
    } else {
      float hd = vel[grow * 2 + 1];
      float c = (float)(k - NSPEED) * HD_STEP;
      f = C_HD * __expf(KAPPA * (__cosf(hd - c) - 1.0f));
    }
    feats[row][k] = f;
  }
  __syncthreads();

  const float2* Ws2 = (const float2*)W_speed;  // [20][256]
  const float2* Wh2 = (const float2*)W_hd;     // [50][256]
  float2 br = ((const float2*)b_rec)[tid];

  for (int r = 0; r < 64; ++r) {
    float a0 = br.x, a1 = br.y;
#pragma unroll
    for (int k = 0; k < NSPEED; ++k) {
      float f = feats[r][k];
      float2 w = Ws2[k * 256 + tid];
      a0 = fmaf(f, w.x, a0);
      a1 = fmaf(f, w.y, a1);
    }
#pragma unroll 10
    for (int k = 0; k < NHD; ++k) {
      float f = feats[r][NSPEED + k];
      float2 w = Wh2[k * 256 + tid];
      a0 = fmaf(f, w.x, a0);
      a1 = fmaf(f, w.y, a1);
    }
    ((float2*)drive)[(size_t)(row0 + r) * 256 + tid] = make_float2(a0, a1);
  }
}

// ---------------------------------------------------------------------------
// Kernel B: col-split RNN scan, W in REGISTERS (f32, no quantization).
// 256 blocks = (batch b, slice s via bid = b + 64*s) x 1024 threads.
// Thread (kg, col) holds W[kg*64..+64)[s*128+col] in 16 float4 regs.
// h_new = relu(W·h + d)  [W holds the full recurrent matrix -- no extra
// identity term; R11's NaN was from double-adding h here].
// h exchanged through hstates with RELAXED agent-scope atomics (execute
// at L3 -> no L1/L2 fences, W/drive stay cached). Monotonic per-batch
// counter barrier; __syncthreads drains vmcnt before the signal add.
// ---------------------------------------------------------------------------
__global__ __launch_bounds__(1024) void rnn_scan6_kernel(
    const float4* __restrict__ wp, const float* __restrict__ drive,
    const float* __restrict__ start_state, float* __restrict__ hstates,
    unsigned* __restrict__ cnt) {
  __shared__ __align__(16) float hf[UNITS];
  __shared__ float pt[1024];
  const int bid = blockIdx.x;
  const int b = bid & 63, s = bid >> 6;  // bid = b + 64*s
  const int tid = threadIdx.x;
  const int col = tid & (CPB - 1);  // 0..127
  const int kg = tid >> 7;          // 0..7 (wave-uniform)
  const int scol = s * CPB + col;

  // Prologue: own W-slice into registers (coalesced float4 loads).
  float4 w[16];
  {
    const float4* base = wp + (s << 14) + (kg << 11) + col;  // k4 = kg*16 + i
#pragma unroll
    for (int i = 0; i < 16; ++i) w[i] = base[i << 7];
  }
  if (tid < 128) ((float4*)hf)[tid] = ((const float4*)start_state)[tid];
  __syncthreads();

  const float* D = drive + (size_t)b * TT * UNITS;
  float* H = hstates + (size_t)b * TT * UNITS;
  unsigned* c = cnt + (b << 5);  // one 128B line per batch

  for (int t = 0; t < TT; ++t) {
    const float4* hv = (const float4*)hf + (kg << 4);
    float a0 = 0.f, a1 = 0.f, a2 = 0.f, a3 = 0.f;
#pragma unroll
    for (int i = 0; i < 16; ++i) {
      float4 h4 = hv[i];  // wave-uniform LDS broadcast
      a0 = fmaf(h4.x, w[i].x, a0);
      a1 = fmaf(h4.y, w[i].y, a1);
      a2 = fmaf(h4.z, w[i].z, a2);
      a3 = fmaf(h4.w, w[i].w, a3);
    }
    pt[tid] = (a0 + a1) + (a2 + a3);
    __syncthreads();
    if (tid < 128) {
      float sum = 0.f;
#pragma unroll
      for (int j = 0; j < 8; ++j) sum += pt[col + (j << 7)];
      float hn = fmaxf(sum + D[t * UNITS + scol], 0.0f);
      // publish own slice straight to L3, also the kernel output
      __hip_atomic_store(&H[t * UNITS + scol], hn, __ATOMIC_RELAXED,
                         __HIP_MEMORY_SCOPE_AGENT);
    }
    if (t == TT - 1) break;
    __syncthreads();  // drains vmcnt(0): stores are in L3 before signaling
    if (tid == 0) {
      __hip_atomic_fetch_add(c, 1u, __ATOMIC_RELAXED,
                             __HIP_MEMORY_SCOPE_AGENT);
      unsigned tgt = (unsigned)(GS * (t + 1));
      while (__hip_atomic_load(c, __ATOMIC_RELAXED,
                               __HIP_MEMORY_SCOPE_AGENT) < tgt)
        __builtin_amdgcn_s_sleep(1);
    }
    __syncthreads();
    asm volatile("" ::: "memory");  // keep reloads below the spin
    if (tid < 128) {  // reload full h_t from L3 (2 x b64 atomic loads)
      unsigned long long p0 = __hip_atomic_load(
          (const unsigned long long*)&H[t * UNITS + tid * 4], __ATOMIC_RELAXED,
          __HIP_MEMORY_SCOPE_AGENT);
      unsigned long long p1 = __hip_atomic_load(
          (const unsigned long long*)&H[t * UNITS + tid * 4 + 2],
          __ATOMIC_RELAXED, __HIP_MEMORY_SCOPE_AGENT);
      float2 f0 = __builtin_bit_cast(float2, p0);
      float2 f1 = __builtin_bit_cast(float2, p1);
      ((float4*)hf)[tid] = make_float4(f0.x, f0.y, f1.x, f1.y);
    }
    __syncthreads();
  }
}

// ---------------------------------------------------------------------------
// Kernel C: out = relu(hstates @ W_out + b_out); M=32768, N=256, K=512
// ---------------------------------------------------------------------------
__global__ __launch_bounds__(256) void out_gemm_kernel(
    const float* __restrict__ A,    // [32768][512]
    const float* __restrict__ Bm,   // [512][256]
    const float* __restrict__ b_out,
    float* __restrict__ C) {        // [32768][256]
  __shared__ float As[32][68];  // transposed, padded
  __shared__ float Bs[32][64];
  const int bm = blockIdx.x, bn = blockIdx.y;
  const int tid = threadIdx.x;
  const int tm = tid / 16, tn = tid % 16;

  float acc[4][4] = {{0.f}};

  for (int k0 = 0; k0 < UNITS; k0 += 32) {
    {
      int ar = tid / 8;
      int ac = (tid % 8) * 4;
#pragma unroll
      for (int p = 0; p < 2; ++p) {
        int row = ar + p * 32;
        float4 v = *(const float4*)&A[(size_t)(bm * 64 + row) * 512 + k0 + ac];
        As[ac + 0][row] = v.x;
        As[ac + 1][row] = v.y;
        As[ac + 2][row] = v.z;
        As[ac + 3][row] = v.w;
      }
      int brr = tid / 16;
      int bc = (tid % 16) * 4;
#pragma unroll
      for (int p = 0; p < 2; ++p) {
        int row = brr + p * 16;
        *(float4*)&Bs[row][bc] =
            *(const float4*)&Bm[(size_t)(k0 + row) * 256 + bn * 64 + bc];
      }
    }
    __syncthreads();
#pragma unroll
    for (int kk = 0; kk < 32; ++kk) {
      float4 av = *(const float4*)&As[kk][tm * 4];
      float4 bv = *(const float4*)&Bs[kk][tn * 4];
      acc[0][0] = fmaf(av.x, bv.x, acc[0][0]);
      acc[0][1] = fmaf(av.x, bv.y, acc[0][1]);
      acc[0][2] = fmaf(av.x, bv.z, acc[0][2]);
      acc[0][3] = fmaf(av.x, bv.w, acc[0][3]);
      acc[1][0] = fmaf(av.y, bv.x, acc[1][0]);
      acc[1][1] = fmaf(av.y, bv.y, acc[1][1]);
      acc[1][2] = fmaf(av.y, bv.z, acc[1][2]);
      acc[1][3] = fmaf(av.y, bv.w, acc[1][3]);
      acc[2][0] = fmaf(av.z, bv.x, acc[2][0]);
      acc[2][1] = fmaf(av.z, bv.y, acc[2][1]);
      acc[2][2] = fmaf(av.z, bv.z, acc[2][2]);
      acc[2][3] = fmaf(av.z, bv.w, acc[2][3]);
      acc[3][0] = fmaf(av.w, bv.x, acc[3][0]);
      acc[3][1] = fmaf(av.w, bv.y, acc[3][1]);
      acc[3][2] = fmaf(av.w, bv.z, acc[3][2]);
      acc[3][3] = fmaf(av.w, bv.w, acc[3][3]);
    }
    __syncthreads();
  }

  float4 bo = *(const float4*)&b_out[bn * 64 + tn * 4];
#pragma unroll
  for (int i = 0; i < 4; ++i) {
    int row = bm * 64 + tm * 4 + i;
    float4 o;
    o.x = fmaxf(acc[i][0] + bo.x, 0.0f);
    o.y = fmaxf(acc[i][1] + bo.y, 0.0f);
    o.z = fmaxf(acc[i][2] + bo.z, 0.0f);
    o.w = fmaxf(acc[i][3] + bo.w, 0.0f);
    *(float4*)&C[(size_t)row * 256 + bn * 64 + tn * 4] = o;
  }
}

// ---------------------------------------------------------------------------
// Kernel D1: EC[b,n,:] = (sum_t out*r) / (sum_t out + T*1e-10)
// ---------------------------------------------------------------------------
__global__ __launch_bounds__(256) void ec_kernel(
    const float* __restrict__ out, const float* __restrict__ r,
    float* __restrict__ EC) {  // [64][256][2]
  const int b = blockIdx.x, n = threadIdx.x;
  const float* ob = out + (size_t)b * TT * NOUT;
  const float2* rb = (const float2*)r + (size_t)b * TT;
  float s = 0.0f, e0 = 0.0f, e1 = 0.0f;
  for (int t = 0; t < TT; ++t) {
    float o = ob[t * NOUT + n];
    float2 rv = rb[t];
    s += o;
    e0 = fmaf(o, rv.x, e0);
    e1 = fmaf(o, rv.y, e1);
  }
  float inv = 1.0f / (s + 5.12e-8f);  // + T*1e-10
  ((float2*)EC)[b * NOUT + n] = make_float2(e0 * inv, e1 * inv);
}

// ---------------------------------------------------------------------------
// Kernel D2: EP[b,t,:] = (sum_n out*EC) / (sum_n out + N*1e-10)
// ---------------------------------------------------------------------------
__global__ __launch_bounds__(256) void ep_kernel(
    const float* __restrict__ out, const float* __restrict__ EC,
    float* __restrict__ EP) {
  const int b = blockIdx.x;
  const int tid = threadIdx.x;
  const int lane = tid & 63, wave = tid >> 6;
  __shared__ float ec0[NOUT], ec1[NOUT];

  float2 e = ((const float2*)EC)[b * NOUT + tid];
  ec0[tid] = e.x;
  ec1[tid] = e.y;
  __syncthreads();

  float4 c0 = *(const float4*)&ec0[lane * 4];
  float4 c1 = *(const float4*)&ec1[lane * 4];

  const float* ob = out + (size_t)b * TT * NOUT;
  float2* epb = (float2*)EP + (size_t)b * TT;

  for (int t = wave; t < TT; t += 4) {
    float4 o = *(const float4*)&ob[t * NOUT + lane * 4];
    float s = o.x + o.y + o.z + o.w;
    float a0 = o.x * c0.x + o.y * c0.y + o.z * c0.z + o.w * c0.w;
    float a1 = o.x * c1.x + o.y * c1.y + o.z * c1.z + o.w * c1.w;
#pragma unroll
    for (int off = 32; off > 0; off >>= 1) {
      s += __shfl_down(s, off);
      a0 += __shfl_down(a0, off);
      a1 += __shfl_down(a1, off);
    }
    if (lane == 0) {
      float inv = 1.0f / (s + 2.56e-8f);  // + NOUT*1e-10
      epb[t] = make_float2(a0 * inv, a1 * inv);
    }
  }
}

// ---------------------------------------------------------------------------
extern "C" void kernel_launch(void* const* d_in, const int* in_sizes, int n_in,
                              void* d_out, int out_size, void* d_ws,
                              size_t ws_size, hipStream_t stream) {
  const float* vel = (const float*)d_in[0];
  const float* r = (const float*)d_in[1];
  const float* start_state = (const float*)d_in[2];
  const float* W_speed = (const float*)d_in[3];
  const float* W_hd = (const float*)d_in[4];
  const float* W_rec = (const float*)d_in[5];
  const float* b_rec = (const float*)d_in[6];
  const float* W_out = (const float*)d_in[7];
  const float* b_out = (const float*)d_in[8];
  float* EP = (float*)d_out;

  char* ws = (char*)d_ws;
  float* drive = (float*)ws;                            // 64 MB
  float* hstates = (float*)(ws + (size_t)67108864);     // 64 MB
  float* outbuf = (float*)ws;                           // reuses drive region
  float4* wpack = (float4*)(ws + (size_t)134217728);    // 1 MB repacked W_rec
  unsigned* cnt = (unsigned*)(ws + (size_t)135266304);  // 64 x 128B counters
  float* EC = (float*)(ws + (size_t)135274496);         // 128 KB

  prep_w4s_kernel<<<256, 256, 0, stream>>>(W_rec, wpack, cnt);
  feat_drive_kernel<<<512, 256, 0, stream>>>(vel, W_speed, W_hd, b_rec, drive);
  rnn_scan6_kernel<<<256, 1024, 0, stream>>>(wpack, drive, start_state,
                                             hstates, cnt);
  out_gemm_kernel<<<dim3(512, 4), 256, 0, stream>>>(hstates, W_out, b_out,
                                                    outbuf);
  ec_kernel<<<64, 256, 0, stream>>>(outbuf, r, EC);
  ep_kernel<<<64, 256, 0, stream>>>(outbuf, EC, EP);
}

// Round 16
// 1390.036 us; speedup vs baseline: 4.6899x; 1.0018x over previous
//
#include <hip/hip_runtime.h>
#include <hip/hip_bf16.h>

// Problem constants
#define BATCH 64
#define TT 512
#define UNITS 512
#define NOUT 256
#define NSPEED 20
#define NHD 50
#define NFEAT 70

// Derived constants
#define SPEED_COEF (-800.0f)                  // -0.5/sd^2, sd = 0.5/20
#define SPEED_STEP (0.5f / 19.0f)             // linspace(0,0.5,20)
#define HD_STEP (6.28318530718f / 49.0f)      // linspace(0,2pi,50)
#define KAPPA 6.2831853f
#define C_HD 0.9783857f                       // 1 / (2*pi*i0e(2*pi)), i0e(2pi)=0.162671

#define GS 4     // CU-slices per batch
#define CPB 128  // columns per scan block

// ---------------------------------------------------------------------------
// Kernel P: repack W_rec f32 [k][col] -> per-slice float4 tiles:
// wp[s*16384 + k4*128 + col] = (W[4k4+0..3][s*128+col]); zero barrier
// counters via agent-scope atomic stores (ws poisoned 0xAA each launch).
// ---------------------------------------------------------------------------
__global__ __launch_bounds__(256) void prep_w4s_kernel(
    const float* __restrict__ W, float4* __restrict__ wp,
    unsigned* __restrict__ cnt) {
  int idx = blockIdx.x * 256 + threadIdx.x;  // 65536
  int s = idx >> 14, k4 = (idx >> 7) & 127, col = idx & 127;
  int gcol = s * CPB + col;
  const float* w0 = W + (size_t)(k4 * 4) * UNITS + gcol;
  wp[idx] = make_float4(w0[0], w0[UNITS], w0[2 * UNITS], w0[3 * UNITS]);
  if (idx < BATCH)
    __hip_atomic_store(&cnt[idx * 32], 0u, __ATOMIC_RELAXED,
                       __HIP_MEMORY_SCOPE_AGENT);
}

// ---------------------------------------------------------------------------
// Kernel A: RBF/VonMises features + drive = sf@W_speed + hf@W_hd + b_rec
// ---------------------------------------------------------------------------
__global__ __launch_bounds__(256) void feat_drive_kernel(
    const float* __restrict__ vel, const float* __restrict__ W_speed,
    const float* __restrict__ W_hd, const float* __restrict__ b_rec,
    float* __restrict__ drive) {
  __shared__ float feats[64][NFEAT];
  const int row0 = blockIdx.x * 64;
  const int tid = threadIdx.x;

  for (int j = tid; j < 64 * NFEAT; j += 256) {
    int row = j / NFEAT, k = j % NFEAT;
    int grow = row0 + row;
    float f;
    if (k < NSPEED) {
      float s = vel[grow * 2 + 0];
      float d = s - (float)k * SPEED_STEP;
      f = __expf(SPEED_COEF * d * d);
    } else {
      float hd = vel[grow * 2 + 1];
      float c = (float)(k - NSPEED) * HD_STEP;
      f = C_HD * __expf(KAPPA * (__cosf(hd - c) - 1.0f));
    }
    feats[row][k] = f;
  }
  __syncthreads();

  const float2* Ws2 = (const float2*)W_speed;  // [20][256]
  const float2* Wh2 = (const float2*)W_hd;     // [50][256]
  float2 br = ((const float2*)b_rec)[tid];

  for (int r = 0; r < 64; ++r) {
    float a0 = br.x, a1 = br.y;
#pragma unroll
    for (int k = 0; k < NSPEED; ++k) {
      float f = feats[r][k];
      float2 w = Ws2[k * 256 + tid];
      a0 = fmaf(f, w.x, a0);
      a1 = fmaf(f, w.y, a1);
    }
#pragma unroll 10
    for (int k = 0; k < NHD; ++k) {
      float f = feats[r][NSPEED + k];
      float2 w = Wh2[k * 256 + tid];
      a0 = fmaf(f, w.x, a0);
      a1 = fmaf(f, w.y, a1);
    }
    ((float2*)drive)[(size_t)(row0 + r) * 256 + tid] = make_float2(a0, a1);
  }
}

// ---------------------------------------------------------------------------
// Kernel B: col-split RNN scan, W in REGISTERS (f32) -- EXACT R12 version
// (known-good). 256 blocks = (batch b, slice s via bid = b + 64*s).
// h exchanged through hstates with relaxed agent-scope atomics (L3);
// monotonic per-batch counter barrier.
// ---------------------------------------------------------------------------
__global__ __launch_bounds__(1024) void rnn_scan6_kernel(
    const float4* __restrict__ wp, const float* __restrict__ drive,
    const float* __restrict__ start_state, float* __restrict__ hstates,
    unsigned* __restrict__ cnt) {
  __shared__ __align__(16) float hf[UNITS];
  __shared__ float pt[1024];
  const int bid = blockIdx.x;
  const int b = bid & 63, s = bid >> 6;  // bid = b + 64*s
  const int tid = threadIdx.x;
  const int col = tid & (CPB - 1);  // 0..127
  const int kg = tid >> 7;          // 0..7 (wave-uniform)
  const int scol = s * CPB + col;

  // Prologue: own W-slice into registers (coalesced float4 loads).
  float4 w[16];
  {
    const float4* base = wp + (s << 14) + (kg << 11) + col;  // k4 = kg*16 + i
#pragma unroll
    for (int i = 0; i < 16; ++i) w[i] = base[i << 7];
  }
  if (tid < 128) ((float4*)hf)[tid] = ((const float4*)start_state)[tid];
  __syncthreads();

  const float* D = drive + (size_t)b * TT * UNITS;
  float* H = hstates + (size_t)b * TT * UNITS;
  unsigned* c = cnt + (b << 5);  // one 128B line per batch

  for (int t = 0; t < TT; ++t) {
    const float4* hv = (const float4*)hf + (kg << 4);
    float a0 = 0.f, a1 = 0.f, a2 = 0.f, a3 = 0.f;
#pragma unroll
    for (int i = 0; i < 16; ++i) {
      float4 h4 = hv[i];  // wave-uniform LDS broadcast
      a0 = fmaf(h4.x, w[i].x, a0);
      a1 = fmaf(h4.y, w[i].y, a1);
      a2 = fmaf(h4.z, w[i].z, a2);
      a3 = fmaf(h4.w, w[i].w, a3);
    }
    pt[tid] = (a0 + a1) + (a2 + a3);
    __syncthreads();
    if (tid < 128) {
      float sum = 0.f;
#pragma unroll
      for (int j = 0; j < 8; ++j) sum += pt[col + (j << 7)];
      float hn = fmaxf(sum + D[t * UNITS + scol], 0.0f);
      // publish own slice straight to L3, also the kernel output
      __hip_atomic_store(&H[t * UNITS + scol], hn, __ATOMIC_RELAXED,
                         __HIP_MEMORY_SCOPE_AGENT);
    }
    if (t == TT - 1) break;
    __syncthreads();  // drains vmcnt(0): stores are in L3 before signaling
    if (tid == 0) {
      __hip_atomic_fetch_add(c, 1u, __ATOMIC_RELAXED,
                             __HIP_MEMORY_SCOPE_AGENT);
      unsigned tgt = (unsigned)(GS * (t + 1));
      while (__hip_atomic_load(c, __ATOMIC_RELAXED,
                               __HIP_MEMORY_SCOPE_AGENT) < tgt)
        __builtin_amdgcn_s_sleep(1);
    }
    __syncthreads();
    asm volatile("" ::: "memory");  // keep reloads below the spin
    if (tid < 128) {  // reload full h_t from L3 (2 x b64 atomic loads)
      unsigned long long p0 = __hip_atomic_load(
          (const unsigned long long*)&H[t * UNITS + tid * 4], __ATOMIC_RELAXED,
          __HIP_MEMORY_SCOPE_AGENT);
      unsigned long long p1 = __hip_atomic_load(
          (const unsigned long long*)&H[t * UNITS + tid * 4 + 2],
          __ATOMIC_RELAXED, __HIP_MEMORY_SCOPE_AGENT);
      float2 f0 = __builtin_bit_cast(float2, p0);
      float2 f1 = __builtin_bit_cast(float2, p1);
      ((float4*)hf)[tid] = make_float4(f0.x, f0.y, f1.x, f1.y);
    }
    __syncthreads();
  }
}

// ---------------------------------------------------------------------------
// Kernel C: out = relu(hstates @ W_out + b_out); M=32768, N=256, K=512.
// 128x128 tile, 256 threads, 8x8 per thread, BK=16: per kk, 4 ds_read_b128
// feed 64 FMAs -> FMA-bound (old 64x64/4x4 was LDS-read-bound).
// ---------------------------------------------------------------------------
__global__ __launch_bounds__(256) void out_gemm_kernel(
    const float* __restrict__ A,    // [32768][512]
    const float* __restrict__ Bm,   // [512][256]
    const float* __restrict__ b_out,
    float* __restrict__ C) {        // [32768][256]
  __shared__ float As[16][132];  // transposed, padded
  __shared__ float Bs[16][132];
  const int bm = blockIdx.x, bn = blockIdx.y;  // bm<256, bn<2
  const int tid = threadIdx.x;
  const int tm = tid >> 4, tn = tid & 15;  // 16x16 thread grid

  float acc[8][8] = {{0.f}};

  for (int k0 = 0; k0 < UNITS; k0 += 16) {
    {
      int ar = tid >> 2;              // 0..63
      int ak = (tid & 3) << 2;        // 0,4,8,12
      float4 v0 = *(const float4*)&A[(size_t)(bm * 128 + ar) * 512 + k0 + ak];
      float4 v1 =
          *(const float4*)&A[(size_t)(bm * 128 + ar + 64) * 512 + k0 + ak];
      As[ak + 0][ar] = v0.x;
      As[ak + 1][ar] = v0.y;
      As[ak + 2][ar] = v0.z;
      As[ak + 3][ar] = v0.w;
      As[ak + 0][ar + 64] = v1.x;
      As[ak + 1][ar + 64] = v1.y;
      As[ak + 2][ar + 64] = v1.z;
      As[ak + 3][ar + 64] = v1.w;
      int bk = tid >> 4;              // 0..15
      int bc = (tid & 15) << 3;       // 0..120
      float4 w0 = *(const float4*)&Bm[(size_t)(k0 + bk) * 256 + bn * 128 + bc];
      float4 w1 =
          *(const float4*)&Bm[(size_t)(k0 + bk) * 256 + bn * 128 + bc + 4];
      *(float4*)&Bs[bk][bc] = w0;
      *(float4*)&Bs[bk][bc + 4] = w1;
    }
    __syncthreads();
#pragma unroll
    for (int kk = 0; kk < 16; ++kk) {
      float4 a0 = *(const float4*)&As[kk][tm * 8];
      float4 a1 = *(const float4*)&As[kk][tm * 8 + 4];
      float4 b0 = *(const float4*)&Bs[kk][tn * 8];
      float4 b1 = *(const float4*)&Bs[kk][tn * 8 + 4];
      float av[8] = {a0.x, a0.y, a0.z, a0.w, a1.x, a1.y, a1.z, a1.w};
      float bv[8] = {b0.x, b0.y, b0.z, b0.w, b1.x, b1.y, b1.z, b1.w};
#pragma unroll
      for (int i = 0; i < 8; ++i)
#pragma unroll
        for (int j = 0; j < 8; ++j) acc[i][j] = fmaf(av[i], bv[j], acc[i][j]);
    }
    __syncthreads();
  }

  float4 bo0 = *(const float4*)&b_out[bn * 128 + tn * 8];
  float4 bo1 = *(const float4*)&b_out[bn * 128 + tn * 8 + 4];
  float bo[8] = {bo0.x, bo0.y, bo0.z, bo0.w, bo1.x, bo1.y, bo1.z, bo1.w};
#pragma unroll
  for (int i = 0; i < 8; ++i) {
    int row = bm * 128 + tm * 8 + i;
    float o[8];
#pragma unroll
    for (int j = 0; j < 8; ++j) o[j] = fmaxf(acc[i][j] + bo[j], 0.0f);
    float* cp = &C[(size_t)row * 256 + bn * 128 + tn * 8];
    *(float4*)cp = make_float4(o[0], o[1], o[2], o[3]);
    *(float4*)(cp + 4) = make_float4(o[4], o[5], o[6], o[7]);
  }
}

// ---------------------------------------------------------------------------
// Kernel D1: EC[b,n,:] = (sum_t out*r) / (sum_t out + T*1e-10)
// ---------------------------------------------------------------------------
__global__ __launch_bounds__(256) void ec_kernel(
    const float* __restrict__ out, const float* __restrict__ r,
    float* __restrict__ EC) {  // [64][256][2]
  const int b = blockIdx.x, n = threadIdx.x;
  const float* ob = out + (size_t)b * TT * NOUT;
  const float2* rb = (const float2*)r + (size_t)b * TT;
  float s = 0.0f, e0 = 0.0f, e1 = 0.0f;
  for (int t = 0; t < TT; ++t) {
    float o = ob[t * NOUT + n];
    float2 rv = rb[t];
    s += o;
    e0 = fmaf(o, rv.x, e0);
    e1 = fmaf(o, rv.y, e1);
  }
  float inv = 1.0f / (s + 5.12e-8f);  // + T*1e-10
  ((float2*)EC)[b * NOUT + n] = make_float2(e0 * inv, e1 * inv);
}

// ---------------------------------------------------------------------------
// Kernel D2: EP[b,t,:] = (sum_n out*EC) / (sum_n out + N*1e-10)
// ---------------------------------------------------------------------------
__global__ __launch_bounds__(256) void ep_kernel(
    const float* __restrict__ out, const float* __restrict__ EC,
    float* __restrict__ EP) {
  const int b = blockIdx.x;
  const int tid = threadIdx.x;
  const int lane = tid & 63, wave = tid >> 6;
  __shared__ float ec0[NOUT], ec1[NOUT];

  float2 e = ((const float2*)EC)[b * NOUT + tid];
  ec0[tid] = e.x;
  ec1[tid] = e.y;
  __syncthreads();

  float4 c0 = *(const float4*)&ec0[lane * 4];
  float4 c1 = *(const float4*)&ec1[lane * 4];

  const float* ob = out + (size_t)b * TT * NOUT;
  float2* epb = (float2*)EP + (size_t)b * TT;

  for (int t = wave; t < TT; t += 4) {
    float4 o = *(const float4*)&ob[t * NOUT + lane * 4];
    float s = o.x + o.y + o.z + o.w;
    float a0 = o.x * c0.x + o.y * c0.y + o.z * c0.z + o.w * c0.w;
    float a1 = o.x * c1.x + o.y * c1.y + o.z * c1.z + o.w * c1.w;
#pragma unroll
    for (int off = 32; off > 0; off >>= 1) {
      s += __shfl_down(s, off);
      a0 += __shfl_down(a0, off);
      a1 += __shfl_down(a1, off);
    }
    if (lane == 0) {
      float inv = 1.0f / (s + 2.56e-8f);  // + NOUT*1e-10
      epb[t] = make_float2(a0 * inv, a1 * inv);
    }
  }
}

// ---------------------------------------------------------------------------
extern "C" void kernel_launch(void* const* d_in, const int* in_sizes, int n_in,
                              void* d_out, int out_size, void* d_ws,
                              size_t ws_size, hipStream_t stream) {
  const float* vel = (const float*)d_in[0];
  const float* r = (const float*)d_in[1];
  const float* start_state = (const float*)d_in[2];
  const float* W_speed = (const float*)d_in[3];
  const float* W_hd = (const float*)d_in[4];
  const float* W_rec = (const float*)d_in[5];
  const float* b_rec = (const float*)d_in[6];
  const float* W_out = (const float*)d_in[7];
  const float* b_out = (const float*)d_in[8];
  float* EP = (float*)d_out;

  char* ws = (char*)d_ws;
  float* drive = (float*)ws;                            // 64 MB
  float* hstates = (float*)(ws + (size_t)67108864);     // 64 MB
  float* outbuf = (float*)ws;                           // reuses drive region
  float4* wpack = (float4*)(ws + (size_t)134217728);    // 1 MB repacked W_rec
  unsigned* cnt = (unsigned*)(ws + (size_t)135266304);  // 64 x 128B counters
  float* EC = (float*)(ws + (size_t)135274496);         // 128 KB

  prep_w4s_kernel<<<256, 256, 0, stream>>>(W_rec, wpack, cnt);
  feat_drive_kernel<<<512, 256, 0, stream>>>(vel, W_speed, W_hd, b_rec, drive);
  rnn_scan6_kernel<<<256, 1024, 0, stream>>>(wpack, drive, start_state,
                                             hstates, cnt);
  out_gemm_kernel<<<dim3(256, 2), 256, 0, stream>>>(hstates, W_out, b_out,
                                                    outbuf);
  ec_kernel<<<64, 256, 0, stream>>>(outbuf, r, EC);
  ep_kernel<<<64, 256, 0, stream>>>(outbuf, EC, EP);
}

// Round 17
// 1277.853 us; speedup vs baseline: 5.1016x; 1.0878x over previous
//
#include <hip/hip_runtime.h>
#include <hip/hip_bf16.h>

// Problem constants
#define BATCH 64
#define TT 512
#define UNITS 512
#define NOUT 256
#define NSPEED 20
#define NHD 50
#define NFEAT 70

// Derived constants
#define SPEED_COEF (-800.0f)                  // -0.5/sd^2, sd = 0.5/20
#define SPEED_STEP (0.5f / 19.0f)             // linspace(0,0.5,20)
#define HD_STEP (6.28318530718f / 49.0f)      // linspace(0,2pi,50)
#define KAPPA 6.2831853f
#define C_HD 0.9783857f                       // 1 / (2*pi*i0e(2*pi)), i0e(2pi)=0.162671

#define GS 4     // CU-slices per batch
#define CPB 128  // columns per scan block

// ---------------------------------------------------------------------------
// Kernel P: repack W_rec f32 [k][col] -> per-slice float4 tiles:
// wp[s*16384 + k4*128 + col] = (W[4k4+0..3][s*128+col]); zero barrier
// counters via agent-scope atomic stores (ws poisoned 0xAA each launch).
// ---------------------------------------------------------------------------
__global__ __launch_bounds__(256) void prep_w4s_kernel(
    const float* __restrict__ W, float4* __restrict__ wp,
    unsigned* __restrict__ cnt) {
  int idx = blockIdx.x * 256 + threadIdx.x;  // 65536
  int s = idx >> 14, k4 = (idx >> 7) & 127, col = idx & 127;
  int gcol = s * CPB + col;
  const float* w0 = W + (size_t)(k4 * 4) * UNITS + gcol;
  wp[idx] = make_float4(w0[0], w0[UNITS], w0[2 * UNITS], w0[3 * UNITS]);
  if (idx < BATCH)
    __hip_atomic_store(&cnt[idx * 32], 0u, __ATOMIC_RELAXED,
                       __HIP_MEMORY_SCOPE_AGENT);
}

// ---------------------------------------------------------------------------
// Kernel A: RBF/VonMises features + drive = sf@W_speed + hf@W_hd + b_rec.
// Register-blocked: rows in 8 groups of 8; each weight float2 loaded ONCE
// per group (8x fewer weight reloads than per-row; weights don't fit L1).
// Accumulation order per row identical to before -> bit-identical drive.
// ---------------------------------------------------------------------------
__global__ __launch_bounds__(256) void feat_drive_kernel(
    const float* __restrict__ vel, const float* __restrict__ W_speed,
    const float* __restrict__ W_hd, const float* __restrict__ b_rec,
    float* __restrict__ drive) {
  __shared__ float feats[64][NFEAT];
  const int row0 = blockIdx.x * 64;
  const int tid = threadIdx.x;

  for (int j = tid; j < 64 * NFEAT; j += 256) {
    int row = j / NFEAT, k = j % NFEAT;
    int grow = row0 + row;
    float f;
    if (k < NSPEED) {
      float s = vel[grow * 2 + 0];
      float d = s - (float)k * SPEED_STEP;
      f = __expf(SPEED_COEF * d * d);
    } else {
      float hd = vel[grow * 2 + 1];
      float c = (float)(k - NSPEED) * HD_STEP;
      f = C_HD * __expf(KAPPA * (__cosf(hd - c) - 1.0f));
    }
    feats[row][k] = f;
  }
  __syncthreads();

  const float2* Ws2 = (const float2*)W_speed;  // [20][256]
  const float2* Wh2 = (const float2*)W_hd;     // [50][256]
  float2 br = ((const float2*)b_rec)[tid];

  for (int rg = 0; rg < 8; ++rg) {
    float a0[8], a1[8];
#pragma unroll
    for (int j = 0; j < 8; ++j) {
      a0[j] = br.x;
      a1[j] = br.y;
    }
#pragma unroll 4
    for (int k = 0; k < NSPEED; ++k) {
      float2 w = Ws2[k * 256 + tid];
#pragma unroll
      for (int j = 0; j < 8; ++j) {
        float f = feats[rg * 8 + j][k];  // wave-uniform LDS broadcast
        a0[j] = fmaf(f, w.x, a0[j]);
        a1[j] = fmaf(f, w.y, a1[j]);
      }
    }
#pragma unroll 5
    for (int k = 0; k < NHD; ++k) {
      float2 w = Wh2[k * 256 + tid];
#pragma unroll
      for (int j = 0; j < 8; ++j) {
        float f = feats[rg * 8 + j][NSPEED + k];
        a0[j] = fmaf(f, w.x, a0[j]);
        a1[j] = fmaf(f, w.y, a1[j]);
      }
    }
#pragma unroll
    for (int j = 0; j < 8; ++j)
      ((float2*)drive)[(size_t)(row0 + rg * 8 + j) * 256 + tid] =
          make_float2(a0[j], a1[j]);
  }
}

// ---------------------------------------------------------------------------
// Kernel B: col-split RNN scan, W in REGISTERS (f32) -- EXACT R12 version
// (known-good). 256 blocks = (batch b, slice s via bid = b + 64*s).
// h exchanged through hstates with relaxed agent-scope atomics (L3);
// monotonic per-batch counter barrier.
// ---------------------------------------------------------------------------
__global__ __launch_bounds__(1024) void rnn_scan6_kernel(
    const float4* __restrict__ wp, const float* __restrict__ drive,
    const float* __restrict__ start_state, float* __restrict__ hstates,
    unsigned* __restrict__ cnt) {
  __shared__ __align__(16) float hf[UNITS];
  __shared__ float pt[1024];
  const int bid = blockIdx.x;
  const int b = bid & 63, s = bid >> 6;  // bid = b + 64*s
  const int tid = threadIdx.x;
  const int col = tid & (CPB - 1);  // 0..127
  const int kg = tid >> 7;          // 0..7 (wave-uniform)
  const int scol = s * CPB + col;

  // Prologue: own W-slice into registers (coalesced float4 loads).
  float4 w[16];
  {
    const float4* base = wp + (s << 14) + (kg << 11) + col;  // k4 = kg*16 + i
#pragma unroll
    for (int i = 0; i < 16; ++i) w[i] = base[i << 7];
  }
  if (tid < 128) ((float4*)hf)[tid] = ((const float4*)start_state)[tid];
  __syncthreads();

  const float* D = drive + (size_t)b * TT * UNITS;
  float* H = hstates + (size_t)b * TT * UNITS;
  unsigned* c = cnt + (b << 5);  // one 128B line per batch

  for (int t = 0; t < TT; ++t) {
    const float4* hv = (const float4*)hf + (kg << 4);
    float a0 = 0.f, a1 = 0.f, a2 = 0.f, a3 = 0.f;
#pragma unroll
    for (int i = 0; i < 16; ++i) {
      float4 h4 = hv[i];  // wave-uniform LDS broadcast
      a0 = fmaf(h4.x, w[i].x, a0);
      a1 = fmaf(h4.y, w[i].y, a1);
      a2 = fmaf(h4.z, w[i].z, a2);
      a3 = fmaf(h4.w, w[i].w, a3);
    }
    pt[tid] = (a0 + a1) + (a2 + a3);
    __syncthreads();
    if (tid < 128) {
      float sum = 0.f;
#pragma unroll
      for (int j = 0; j < 8; ++j) sum += pt[col + (j << 7)];
      float hn = fmaxf(sum + D[t * UNITS + scol], 0.0f);
      // publish own slice straight to L3, also the kernel output
      __hip_atomic_store(&H[t * UNITS + scol], hn, __ATOMIC_RELAXED,
                         __HIP_MEMORY_SCOPE_AGENT);
    }
    if (t == TT - 1) break;
    __syncthreads();  // drains vmcnt(0): stores are in L3 before signaling
    if (tid == 0) {
      __hip_atomic_fetch_add(c, 1u, __ATOMIC_RELAXED,
                             __HIP_MEMORY_SCOPE_AGENT);
      unsigned tgt = (unsigned)(GS * (t + 1));
      while (__hip_atomic_load(c, __ATOMIC_RELAXED,
                               __HIP_MEMORY_SCOPE_AGENT) < tgt)
        __builtin_amdgcn_s_sleep(1);
    }
    __syncthreads();
    asm volatile("" ::: "memory");  // keep reloads below the spin
    if (tid < 128) {  // reload full h_t from L3 (2 x b64 atomic loads)
      unsigned long long p0 = __hip_atomic_load(
          (const unsigned long long*)&H[t * UNITS + tid * 4], __ATOMIC_RELAXED,
          __HIP_MEMORY_SCOPE_AGENT);
      unsigned long long p1 = __hip_atomic_load(
          (const unsigned long long*)&H[t * UNITS + tid * 4 + 2],
          __ATOMIC_RELAXED, __HIP_MEMORY_SCOPE_AGENT);
      float2 f0 = __builtin_bit_cast(float2, p0);
      float2 f1 = __builtin_bit_cast(float2, p1);
      ((float4*)hf)[tid] = make_float4(f0.x, f0.y, f1.x, f1.y);
    }
    __syncthreads();
  }
}

// ---------------------------------------------------------------------------
// Kernel C: out = relu(hstates @ W_out + b_out); M=32768, N=256, K=512.
// 128x128 tile, 256 threads, 8x8 per thread, BK=16.
// ---------------------------------------------------------------------------
__global__ __launch_bounds__(256) void out_gemm_kernel(
    const float* __restrict__ A,    // [32768][512]
    const float* __restrict__ Bm,   // [512][256]
    const float* __restrict__ b_out,
    float* __restrict__ C) {        // [32768][256]
  __shared__ float As[16][132];  // transposed, padded
  __shared__ float Bs[16][132];
  const int bm = blockIdx.x, bn = blockIdx.y;  // bm<256, bn<2
  const int tid = threadIdx.x;
  const int tm = tid >> 4, tn = tid & 15;  // 16x16 thread grid

  float acc[8][8] = {{0.f}};

  for (int k0 = 0; k0 < UNITS; k0 += 16) {
    {
      int ar = tid >> 2;              // 0..63
      int ak = (tid & 3) << 2;        // 0,4,8,12
      float4 v0 = *(const float4*)&A[(size_t)(bm * 128 + ar) * 512 + k0 + ak];
      float4 v1 =
          *(const float4*)&A[(size_t)(bm * 128 + ar + 64) * 512 + k0 + ak];
      As[ak + 0][ar] = v0.x;
      As[ak + 1][ar] = v0.y;
      As[ak + 2][ar] = v0.z;
      As[ak + 3][ar] = v0.w;
      As[ak + 0][ar + 64] = v1.x;
      As[ak + 1][ar + 64] = v1.y;
      As[ak + 2][ar + 64] = v1.z;
      As[ak + 3][ar + 64] = v1.w;
      int bk = tid >> 4;              // 0..15
      int bc = (tid & 15) << 3;       // 0..120
      float4 w0 = *(const float4*)&Bm[(size_t)(k0 + bk) * 256 + bn * 128 + bc];
      float4 w1 =
          *(const float4*)&Bm[(size_t)(k0 + bk) * 256 + bn * 128 + bc + 4];
      *(float4*)&Bs[bk][bc] = w0;
      *(float4*)&Bs[bk][bc + 4] = w1;
    }
    __syncthreads();
#pragma unroll
    for (int kk = 0; kk < 16; ++kk) {
      float4 a0 = *(const float4*)&As[kk][tm * 8];
      float4 a1 = *(const float4*)&As[kk][tm * 8 + 4];
      float4 b0 = *(const float4*)&Bs[kk][tn * 8];
      float4 b1 = *(const float4*)&Bs[kk][tn * 8 + 4];
      float av[8] = {a0.x, a0.y, a0.z, a0.w, a1.x, a1.y, a1.z, a1.w};
      float bv[8] = {b0.x, b0.y, b0.z, b0.w, b1.x, b1.y, b1.z, b1.w};
#pragma unroll
      for (int i = 0; i < 8; ++i)
#pragma unroll
        for (int j = 0; j < 8; ++j) acc[i][j] = fmaf(av[i], bv[j], acc[i][j]);
    }
    __syncthreads();
  }

  float4 bo0 = *(const float4*)&b_out[bn * 128 + tn * 8];
  float4 bo1 = *(const float4*)&b_out[bn * 128 + tn * 8 + 4];
  float bo[8] = {bo0.x, bo0.y, bo0.z, bo0.w, bo1.x, bo1.y, bo1.z, bo1.w};
#pragma unroll
  for (int i = 0; i < 8; ++i) {
    int row = bm * 128 + tm * 8 + i;
    float o[8];
#pragma unroll
    for (int j = 0; j < 8; ++j) o[j] = fmaxf(acc[i][j] + bo[j], 0.0f);
    float* cp = &C[(size_t)row * 256 + bn * 128 + tn * 8];
    *(float4*)cp = make_float4(o[0], o[1], o[2], o[3]);
    *(float4*)(cp + 4) = make_float4(o[4], o[5], o[6], o[7]);
  }
}

// ---------------------------------------------------------------------------
// Kernel D1: EC[b,n,:] = (sum_t out*r) / (sum_t out + T*1e-10)
// ---------------------------------------------------------------------------
__global__ __launch_bounds__(256) void ec_kernel(
    const float* __restrict__ out, const float* __restrict__ r,
    float* __restrict__ EC) {  // [64][256][2]
  const int b = blockIdx.x, n = threadIdx.x;
  const float* ob = out + (size_t)b * TT * NOUT;
  const float2* rb = (const float2*)r + (size_t)b * TT;
  float s = 0.0f, e0 = 0.0f, e1 = 0.0f;
  for (int t = 0; t < TT; ++t) {
    float o = ob[t * NOUT + n];
    float2 rv = rb[t];
    s += o;
    e0 = fmaf(o, rv.x, e0);
    e1 = fmaf(o, rv.y, e1);
  }
  float inv = 1.0f / (s + 5.12e-8f);  // + T*1e-10
  ((float2*)EC)[b * NOUT + n] = make_float2(e0 * inv, e1 * inv);
}

// ---------------------------------------------------------------------------
// Kernel D2: EP[b,t,:] = (sum_n out*EC) / (sum_n out + N*1e-10)
// ---------------------------------------------------------------------------
__global__ __launch_bounds__(256) void ep_kernel(
    const float* __restrict__ out, const float* __restrict__ EC,
    float* __restrict__ EP) {
  const int b = blockIdx.x;
  const int tid = threadIdx.x;
  const int lane = tid & 63, wave = tid >> 6;
  __shared__ float ec0[NOUT], ec1[NOUT];

  float2 e = ((const float2*)EC)[b * NOUT + tid];
  ec0[tid] = e.x;
  ec1[tid] = e.y;
  __syncthreads();

  float4 c0 = *(const float4*)&ec0[lane * 4];
  float4 c1 = *(const float4*)&ec1[lane * 4];

  const float* ob = out + (size_t)b * TT * NOUT;
  float2* epb = (float2*)EP + (size_t)b * TT;

  for (int t = wave; t < TT; t += 4) {
    float4 o = *(const float4*)&ob[t * NOUT + lane * 4];
    float s = o.x + o.y + o.z + o.w;
    float a0 = o.x * c0.x + o.y * c0.y + o.z * c0.z + o.w * c0.w;
    float a1 = o.x * c1.x + o.y * c1.y + o.z * c1.z + o.w * c1.w;
#pragma unroll
    for (int off = 32; off > 0; off >>= 1) {
      s += __shfl_down(s, off);
      a0 += __shfl_down(a0, off);
      a1 += __shfl_down(a1, off);
    }
    if (lane == 0) {
      float inv = 1.0f / (s + 2.56e-8f);  // + NOUT*1e-10
      epb[t] = make_float2(a0 * inv, a1 * inv);
    }
  }
}

// ---------------------------------------------------------------------------
extern "C" void kernel_launch(void* const* d_in, const int* in_sizes, int n_in,
                              void* d_out, int out_size, void* d_ws,
                              size_t ws_size, hipStream_t stream) {
  const float* vel = (const float*)d_in[0];
  const float* r = (const float*)d_in[1];
  const float* start_state = (const float*)d_in[2];
  const float* W_speed = (const float*)d_in[3];
  const float* W_hd = (const float*)d_in[4];
  const float* W_rec = (const float*)d_in[5];
  const float* b_rec = (const float*)d_in[6];
  const float* W_out = (const float*)d_in[7];
  const float* b_out = (const float*)d_in[8];
  float* EP = (float*)d_out;

  char* ws = (char*)d_ws;
  float* drive = (float*)ws;                            // 64 MB
  float* hstates = (float*)(ws + (size_t)67108864);     // 64 MB
  float* outbuf = (float*)ws;                           // reuses drive region
  float4* wpack = (float4*)(ws + (size_t)134217728);    // 1 MB repacked W_rec
  unsigned* cnt = (unsigned*)(ws + (size_t)135266304);  // 64 x 128B counters
  float* EC = (float*)(ws + (size_t)135274496);         // 128 KB

  prep_w4s_kernel<<<256, 256, 0, stream>>>(W_rec, wpack, cnt);
  feat_drive_kernel<<<512, 256, 0, stream>>>(vel, W_speed, W_hd, b_rec, drive);
  rnn_scan6_kernel<<<256, 1024, 0, stream>>>(wpack, drive, start_state,
                                             hstates, cnt);
  out_gemm_kernel<<<dim3(256, 2), 256, 0, stream>>>(hstates, W_out, b_out,
                                                    outbuf);
  ec_kernel<<<64, 256, 0, stream>>>(outbuf, r, EC);
  ep_kernel<<<64, 256, 0, stream>>>(outbuf, EC, EP);
}

// Round 18
// 1252.629 us; speedup vs baseline: 5.2043x; 1.0201x over previous
//
#include <hip/hip_runtime.h>
#include <hip/hip_bf16.h>

// Problem constants
#define BATCH 64
#define TT 512
#define UNITS 512
#define NOUT 256
#define NSPEED 20
#define NHD 50
#define NFEAT 70

// Derived constants
#define SPEED_COEF (-800.0f)                  // -0.5/sd^2, sd = 0.5/20
#define SPEED_STEP (0.5f / 19.0f)             // linspace(0,0.5,20)
#define HD_STEP (6.28318530718f / 49.0f)      // linspace(0,2pi,50)
#define KAPPA 6.2831853f
#define C_HD 0.9783857f                       // 1 / (2*pi*i0e(2*pi)), i0e(2pi)=0.162671

#define GS 4     // CU-slices per batch
#define CPB 128  // columns per scan block
#define POISON 0xAAAAAAAAu  // sign bit set -> can never equal a relu output

// ---------------------------------------------------------------------------
// Kernel Z: poison hstates with 0xAA (sign-bit-1 sentinel). Guarantees every
// launch starts from poison regardless of harness behavior; kernel-boundary
// cache flush makes it globally visible before the scan runs.
// 4096 blocks x 256 thr x 64 B = 64 MB.
// ---------------------------------------------------------------------------
__global__ __launch_bounds__(256) void clear_h_kernel(uint4* __restrict__ H) {
  size_t i = (size_t)(blockIdx.x * 256 + threadIdx.x) * 4;
  uint4 p = make_uint4(POISON, POISON, POISON, POISON);
  H[i + 0] = p;
  H[i + 1] = p;
  H[i + 2] = p;
  H[i + 3] = p;
}

// ---------------------------------------------------------------------------
// Kernel P: repack W_rec f32 [k][col] -> per-slice float4 tiles:
// wp[s*16384 + k4*128 + col] = (W[4k4+0..3][s*128+col]).
// ---------------------------------------------------------------------------
__global__ __launch_bounds__(256) void prep_w4s_kernel(
    const float* __restrict__ W, float4* __restrict__ wp) {
  int idx = blockIdx.x * 256 + threadIdx.x;  // 65536
  int s = idx >> 14, k4 = (idx >> 7) & 127, col = idx & 127;
  int gcol = s * CPB + col;
  const float* w0 = W + (size_t)(k4 * 4) * UNITS + gcol;
  wp[idx] = make_float4(w0[0], w0[UNITS], w0[2 * UNITS], w0[3 * UNITS]);
}

// ---------------------------------------------------------------------------
// Kernel A: RBF/VonMises features + drive = sf@W_speed + hf@W_hd + b_rec.
// Register-blocked: rows in 8 groups of 8 (R17: weight traffic / 8).
// ---------------------------------------------------------------------------
__global__ __launch_bounds__(256) void feat_drive_kernel(
    const float* __restrict__ vel, const float* __restrict__ W_speed,
    const float* __restrict__ W_hd, const float* __restrict__ b_rec,
    float* __restrict__ drive) {
  __shared__ float feats[64][NFEAT];
  const int row0 = blockIdx.x * 64;
  const int tid = threadIdx.x;

  for (int j = tid; j < 64 * NFEAT; j += 256) {
    int row = j / NFEAT, k = j % NFEAT;
    int grow = row0 + row;
    float f;
    if (k < NSPEED) {
      float s = vel[grow * 2 + 0];
      float d = s - (float)k * SPEED_STEP;
      f = __expf(SPEED_COEF * d * d);
    } else {
      float hd = vel[grow * 2 + 1];
      float c = (float)(k - NSPEED) * HD_STEP;
      f = C_HD * __expf(KAPPA * (__cosf(hd - c) - 1.0f));
    }
    feats[row][k] = f;
  }
  __syncthreads();

  const float2* Ws2 = (const float2*)W_speed;  // [20][256]
  const float2* Wh2 = (const float2*)W_hd;     // [50][256]
  float2 br = ((const float2*)b_rec)[tid];

  for (int rg = 0; rg < 8; ++rg) {
    float a0[8], a1[8];
#pragma unroll
    for (int j = 0; j < 8; ++j) {
      a0[j] = br.x;
      a1[j] = br.y;
    }
#pragma unroll 4
    for (int k = 0; k < NSPEED; ++k) {
      float2 w = Ws2[k * 256 + tid];
#pragma unroll
      for (int j = 0; j < 8; ++j) {
        float f = feats[rg * 8 + j][k];
        a0[j] = fmaf(f, w.x, a0[j]);
        a1[j] = fmaf(f, w.y, a1[j]);
      }
    }
#pragma unroll 5
    for (int k = 0; k < NHD; ++k) {
      float2 w = Wh2[k * 256 + tid];
#pragma unroll
      for (int j = 0; j < 8; ++j) {
        float f = feats[rg * 8 + j][NSPEED + k];
        a0[j] = fmaf(f, w.x, a0[j]);
        a1[j] = fmaf(f, w.y, a1[j]);
      }
    }
#pragma unroll
    for (int j = 0; j < 8; ++j)
      ((float2*)drive)[(size_t)(row0 + rg * 8 + j) * 256 + tid] =
          make_float2(a0[j], a1[j]);
  }
}

// ---------------------------------------------------------------------------
// Kernel B: col-split RNN scan, W in registers, DATAFLOW sync (no counter).
// 256 blocks = (batch b, slice s). Each step: matvec own 128 cols, store
// slice to H via relaxed agent atomics (straight to L3) + own LDS, then
// 96 threads poll the 96 remote float4-groups of H[t] until != POISON.
// Sound because h = relu(..) >= 0 (sign bit 0) can never equal POISON
// (sign bit 1), each word is written exactly once after the poison-clear,
// and there is no cross-variable ordering assumption at all.
// ---------------------------------------------------------------------------
__global__ __launch_bounds__(1024) void rnn_scan8_kernel(
    const float4* __restrict__ wp, const float* __restrict__ drive,
    const float* __restrict__ start_state, float* __restrict__ hstates) {
  __shared__ __align__(16) float hf[UNITS];
  __shared__ float pt[1024];
  const int bid = blockIdx.x;
  const int b = bid & 63, s = bid >> 6;  // bid = b + 64*s
  const int tid = threadIdx.x;
  const int col = tid & (CPB - 1);  // 0..127
  const int kg = tid >> 7;          // 0..7 (wave-uniform)
  const int scol = (s << 7) + col;

  // Prologue: own W-slice into registers (coalesced float4 loads).
  float4 w[16];
  {
    const float4* base = wp + (s << 14) + (kg << 11) + col;  // k4 = kg*16 + i
#pragma unroll
    for (int i = 0; i < 16; ++i) w[i] = base[i << 7];
  }
  if (tid < 128) ((float4*)hf)[tid] = ((const float4*)start_state)[tid];
  __syncthreads();

  const float* D = drive + (size_t)b * TT * UNITS;
  float* H = hstates + (size_t)b * TT * UNITS;

  for (int t = 0; t < TT; ++t) {
    const float4* hv = (const float4*)hf + (kg << 4);
    float a0 = 0.f, a1 = 0.f, a2 = 0.f, a3 = 0.f;
#pragma unroll
    for (int i = 0; i < 16; ++i) {
      float4 h4 = hv[i];  // wave-uniform LDS broadcast
      a0 = fmaf(h4.x, w[i].x, a0);
      a1 = fmaf(h4.y, w[i].y, a1);
      a2 = fmaf(h4.z, w[i].z, a2);
      a3 = fmaf(h4.w, w[i].w, a3);
    }
    pt[tid] = (a0 + a1) + (a2 + a3);
    __syncthreads();
    if (tid < 128) {
      float sum = 0.f;
#pragma unroll
      for (int j = 0; j < 8; ++j) sum += pt[col + (j << 7)];
      float hn = fmaxf(sum + D[t * UNITS + scol], 0.0f);
      // publish own slice straight to L3 (also the kernel output)...
      __hip_atomic_store(&H[t * UNITS + scol], hn, __ATOMIC_RELAXED,
                         __HIP_MEMORY_SCOPE_AGENT);
      hf[scol] = hn;  // ...and into our own LDS copy directly
    }
    if (t == TT - 1) break;
    if (tid < 96) {  // poll the 96 remote float4-groups of h_t
      int grp = tid < (s << 5) ? tid : tid + 32;  // skip own 32 groups
      const unsigned long long* src =
          (const unsigned long long*)&H[t * UNITS + (grp << 2)];
      unsigned long long v0, v1;
      do {
        v0 = __hip_atomic_load(src, __ATOMIC_RELAXED,
                               __HIP_MEMORY_SCOPE_AGENT);
      } while ((unsigned)v0 == POISON || (unsigned)(v0 >> 32) == POISON);
      do {
        v1 = __hip_atomic_load(src + 1, __ATOMIC_RELAXED,
                               __HIP_MEMORY_SCOPE_AGENT);
      } while ((unsigned)v1 == POISON || (unsigned)(v1 >> 32) == POISON);
      float2 f0 = __builtin_bit_cast(float2, v0);
      float2 f1 = __builtin_bit_cast(float2, v1);
      ((float4*)hf)[grp] = make_float4(f0.x, f0.y, f1.x, f1.y);
    }
    __syncthreads();
  }
}

// ---------------------------------------------------------------------------
// Kernel C: out = relu(hstates @ W_out + b_out); M=32768, N=256, K=512.
// 128x128 tile, 256 threads, 8x8 per thread, BK=16.
// ---------------------------------------------------------------------------
__global__ __launch_bounds__(256) void out_gemm_kernel(
    const float* __restrict__ A,    // [32768][512]
    const float* __restrict__ Bm,   // [512][256]
    const float* __restrict__ b_out,
    float* __restrict__ C) {        // [32768][256]
  __shared__ float As[16][132];  // transposed, padded
  __shared__ float Bs[16][132];
  const int bm = blockIdx.x, bn = blockIdx.y;  // bm<256, bn<2
  const int tid = threadIdx.x;
  const int tm = tid >> 4, tn = tid & 15;  // 16x16 thread grid

  float acc[8][8] = {{0.f}};

  for (int k0 = 0; k0 < UNITS; k0 += 16) {
    {
      int ar = tid >> 2;              // 0..63
      int ak = (tid & 3) << 2;        // 0,4,8,12
      float4 v0 = *(const float4*)&A[(size_t)(bm * 128 + ar) * 512 + k0 + ak];
      float4 v1 =
          *(const float4*)&A[(size_t)(bm * 128 + ar + 64) * 512 + k0 + ak];
      As[ak + 0][ar] = v0.x;
      As[ak + 1][ar] = v0.y;
      As[ak + 2][ar] = v0.z;
      As[ak + 3][ar] = v0.w;
      As[ak + 0][ar + 64] = v1.x;
      As[ak + 1][ar + 64] = v1.y;
      As[ak + 2][ar + 64] = v1.z;
      As[ak + 3][ar + 64] = v1.w;
      int bk = tid >> 4;              // 0..15
      int bc = (tid & 15) << 3;       // 0..120
      float4 w0 = *(const float4*)&Bm[(size_t)(k0 + bk) * 256 + bn * 128 + bc];
      float4 w1 =
          *(const float4*)&Bm[(size_t)(k0 + bk) * 256 + bn * 128 + bc + 4];
      *(float4*)&Bs[bk][bc] = w0;
      *(float4*)&Bs[bk][bc + 4] = w1;
    }
    __syncthreads();
#pragma unroll
    for (int kk = 0; kk < 16; ++kk) {
      float4 a0 = *(const float4*)&As[kk][tm * 8];
      float4 a1 = *(const float4*)&As[kk][tm * 8 + 4];
      float4 b0 = *(const float4*)&Bs[kk][tn * 8];
      float4 b1 = *(const float4*)&Bs[kk][tn * 8 + 4];
      float av[8] = {a0.x, a0.y, a0.z, a0.w, a1.x, a1.y, a1.z, a1.w};
      float bv[8] = {b0.x, b0.y, b0.z, b0.w, b1.x, b1.y, b1.z, b1.w};
#pragma unroll
      for (int i = 0; i < 8; ++i)
#pragma unroll
        for (int j = 0; j < 8; ++j) acc[i][j] = fmaf(av[i], bv[j], acc[i][j]);
    }
    __syncthreads();
  }

  float4 bo0 = *(const float4*)&b_out[bn * 128 + tn * 8];
  float4 bo1 = *(const float4*)&b_out[bn * 128 + tn * 8 + 4];
  float bo[8] = {bo0.x, bo0.y, bo0.z, bo0.w, bo1.x, bo1.y, bo1.z, bo1.w};
#pragma unroll
  for (int i = 0; i < 8; ++i) {
    int row = bm * 128 + tm * 8 + i;
    float o[8];
#pragma unroll
    for (int j = 0; j < 8; ++j) o[j] = fmaxf(acc[i][j] + bo[j], 0.0f);
    float* cp = &C[(size_t)row * 256 + bn * 128 + tn * 8];
    *(float4*)cp = make_float4(o[0], o[1], o[2], o[3]);
    *(float4*)(cp + 4) = make_float4(o[4], o[5], o[6], o[7]);
  }
}

// ---------------------------------------------------------------------------
// Kernel D1: EC[b,n,:] = (sum_t out*r) / (sum_t out + T*1e-10)
// ---------------------------------------------------------------------------
__global__ __launch_bounds__(256) void ec_kernel(
    const float* __restrict__ out, const float* __restrict__ r,
    float* __restrict__ EC) {  // [64][256][2]
  const int b = blockIdx.x, n = threadIdx.x;
  const float* ob = out + (size_t)b * TT * NOUT;
  const float2* rb = (const float2*)r + (size_t)b * TT;
  float s = 0.0f, e0 = 0.0f, e1 = 0.0f;
  for (int t = 0; t < TT; ++t) {
    float o = ob[t * NOUT + n];
    float2 rv = rb[t];
    s += o;
    e0 = fmaf(o, rv.x, e0);
    e1 = fmaf(o, rv.y, e1);
  }
  float inv = 1.0f / (s + 5.12e-8f);  // + T*1e-10
  ((float2*)EC)[b * NOUT + n] = make_float2(e0 * inv, e1 * inv);
}

// ---------------------------------------------------------------------------
// Kernel D2: EP[b,t,:] = (sum_n out*EC) / (sum_n out + N*1e-10)
// ---------------------------------------------------------------------------
__global__ __launch_bounds__(256) void ep_kernel(
    const float* __restrict__ out, const float* __restrict__ EC,
    float* __restrict__ EP) {
  const int b = blockIdx.x;
  const int tid = threadIdx.x;
  const int lane = tid & 63, wave = tid >> 6;
  __shared__ float ec0[NOUT], ec1[NOUT];

  float2 e = ((const float2*)EC)[b * NOUT + tid];
  ec0[tid] = e.x;
  ec1[tid] = e.y;
  __syncthreads();

  float4 c0 = *(const float4*)&ec0[lane * 4];
  float4 c1 = *(const float4*)&ec1[lane * 4];

  const float* ob = out + (size_t)b * TT * NOUT;
  float2* epb = (float2*)EP + (size_t)b * TT;

  for (int t = wave; t < TT; t += 4) {
    float4 o = *(const float4*)&ob[t * NOUT + lane * 4];
    float s = o.x + o.y + o.z + o.w;
    float a0 = o.x * c0.x + o.y * c0.y + o.z * c0.z + o.w * c0.w;
    float a1 = o.x * c1.x + o.y * c1.y + o.z * c1.z + o.w * c1.w;
#pragma unroll
    for (int off = 32; off > 0; off >>= 1) {
      s += __shfl_down(s, off);
      a0 += __shfl_down(a0, off);
      a1 += __shfl_down(a1, off);
    }
    if (lane == 0) {
      float inv = 1.0f / (s + 2.56e-8f);  // + NOUT*1e-10
      epb[t] = make_float2(a0 * inv, a1 * inv);
    }
  }
}

// ---------------------------------------------------------------------------
extern "C" void kernel_launch(void* const* d_in, const int* in_sizes, int n_in,
                              void* d_out, int out_size, void* d_ws,
                              size_t ws_size, hipStream_t stream) {
  const float* vel = (const float*)d_in[0];
  const float* r = (const float*)d_in[1];
  const float* start_state = (const float*)d_in[2];
  const float* W_speed = (const float*)d_in[3];
  const float* W_hd = (const float*)d_in[4];
  const float* W_rec = (const float*)d_in[5];
  const float* b_rec = (const float*)d_in[6];
  const float* W_out = (const float*)d_in[7];
  const float* b_out = (const float*)d_in[8];
  float* EP = (float*)d_out;

  char* ws = (char*)d_ws;
  float* drive = (float*)ws;                            // 64 MB
  float* hstates = (float*)(ws + (size_t)67108864);     // 64 MB
  float* outbuf = (float*)ws;                           // reuses drive region
  float4* wpack = (float4*)(ws + (size_t)134217728);    // 1 MB repacked W_rec
  float* EC = (float*)(ws + (size_t)135274496);         // 128 KB

  clear_h_kernel<<<4096, 256, 0, stream>>>((uint4*)hstates);
  prep_w4s_kernel<<<256, 256, 0, stream>>>(W_rec, wpack);
  feat_drive_kernel<<<512, 256, 0, stream>>>(vel, W_speed, W_hd, b_rec, drive);
  rnn_scan8_kernel<<<256, 1024, 0, stream>>>(wpack, drive, start_state,
                                             hstates);
  out_gemm_kernel<<<dim3(256, 2), 256, 0, stream>>>(hstates, W_out, b_out,
                                                    outbuf);
  ec_kernel<<<64, 256, 0, stream>>>(outbuf, r, EC);
  ep_kernel<<<64, 256, 0, stream>>>(outbuf, EC, EP);
}